// Round 1
// baseline (791.927 us; speedup 1.0000x reference)
//
#include <hip/hip_runtime.h>

// Problem constants (AlignmentMatrix): B=128, L1=1024, L2=128, H2=600
static constexpr int Bn  = 128;
static constexpr int L1c = 1024;
static constexpr int L2c = 128;
static constexpr int H2c = 600;

#define BM 128
#define BN 128
#define BK 64
#define LDK 72              // BK + 8 pad shorts; row stride 144 B (16B-aligned, non-pow2 banks)
static constexpr int NCHUNK = (H2c + BK - 1) / BK;   // 10 (last chunk: 24 valid cols, zero-killed via w=0)

typedef __attribute__((ext_vector_type(8))) __bf16 bf16x8;
typedef __attribute__((ext_vector_type(4))) float  f32x4;

// packed f32x2 -> bf16x2 (RNE), single VOP3 inst on gfx950
__device__ __forceinline__ unsigned int cvt_pk_bf16(float lo, float hi) {
    unsigned int r;
    asm("v_cvt_pk_bf16_f32 %0, %1, %2" : "=v"(r) : "v"(lo), "v"(hi));
    return r;
}

// 512 threads = 8 waves in a 4x2 grid of 32x64 sub-tiles.
// Pipeline: regs hold chunk k at loop top -> convert+ds_write, reissuing each row's
// chunk-k+1 load right after its last use (max overlap) -> barrier -> MFMA -> barrier.
__global__ __launch_bounds__(512, 4)
void align_kernel(const float* __restrict__ ctx, const float* __restrict__ asp,
                  const float* __restrict__ w_u, float* __restrict__ out)
{
    __shared__ unsigned short As[BM * LDK];   // 18432 B, (ctx*w3) in bf16
    __shared__ unsigned short Bs[BN * LDK];   // 18432 B, asp in bf16
    __shared__ float sA[BM];                  // s_ctx for block rows
    __shared__ float sB[BN];                  // s_asp for block cols

    // XCD-aware bijective decode: id = 8*(rt + 8*bq) + xcd ; b = xcd + 8*bq.
    // All 8 row-tiles of batch b share XCD (b&7) AND are dispatched consecutively,
    // so asp[b] (300 KB) is fetched once into that XCD's L2 and re-read 7x from L2.
    const int id   = blockIdx.x;
    const int xcd  = id & 7;
    const int slot = id >> 3;
    const int rt   = slot & 7;    // row tile 0..7
    const int bq   = slot >> 3;   // 0..15
    const int b    = xcd + 8 * bq;
    const int rowBase = rt * BM;

    const int tid  = threadIdx.x;
    const int lane = tid & 63;
    const int wave = tid >> 6;     // 0..7
    const int wm   = wave >> 1;    // 0..3: 32-row band
    const int wn   = wave & 1;     // 0..1: 64-col half
    const int quad = lane >> 4;
    const int l15  = lane & 15;

    const float* ctx_base = ctx + ((size_t)b * L1c + rowBase) * H2c;
    const float* asp_base = asp + (size_t)b * L2c * H2c;
    const float* w1 = w_u;
    const float* w2 = w_u + H2c;
    const float* w3 = w_u + 2 * H2c;

    // staging: thread (srow,scg) covers rows {srow+32i, i<4}, cols [scg*4, scg*4+3]
    const int srow = tid >> 4;     // 0..31
    const int scg  = tid & 15;     // 0..15
    const int d0   = scg * 4;      // 0..60

    f32x4 acc[2][4];
    const f32x4 zero4 = {0.f, 0.f, 0.f, 0.f};
#pragma unroll
    for (int i = 0; i < 2; i++)
#pragma unroll
        for (int j = 0; j < 4; j++) acc[i][j] = zero4;

    float sctxp[4], saspp[4];
#pragma unroll
    for (int i = 0; i < 4; i++) { sctxp[i] = 0.f; saspp[i] = 0.f; }

    float4 Apre[4], Bpre[4], w1v, w2v, w3v;

    // ---- prologue: load chunk 0 (always fully valid) ----
    {
        const int kd = d0;
        w1v = *(const float4*)(w1 + kd);
        w2v = *(const float4*)(w2 + kd);
        w3v = *(const float4*)(w3 + kd);
#pragma unroll
        for (int i = 0; i < 4; i++) {
            const int row = srow + i * 32;
            Apre[i] = *(const float4*)(ctx_base + (size_t)row * H2c + kd);
            Bpre[i] = *(const float4*)(asp_base + (size_t)row * H2c + kd);
        }
    }

    for (int kc = 0; kc < NCHUNK; kc++) {
        // next-chunk column for this thread; clamp into bounds (branchless tail):
        // beyond H2c we load real (finite) floats at a clamped address and kill the
        // A-side contribution with zeroed w vectors -> staged A cols are exact 0,
        // so garbage B cols multiply against 0 in the MFMA. H2c%4==0 so a float4
        // is either wholly valid or wholly dead.
        const int  kdn  = (kc + 1) * BK + d0;
        const int  kdc  = (kdn <= H2c - 4) ? kdn : (H2c - 4);
        const bool wval = (kdn < H2c);
        const bool pref = (kc + 1 < NCHUNK);

        // ---- convert + write chunk kc from regs; fuse rank-1 partial dots;
        //      reissue each row's next-chunk load right after its last use ----
#pragma unroll
        for (int i = 0; i < 4; i++) {
            const int row = srow + i * 32;
            float4 av = Apre[i];
            sctxp[i] += av.x * w1v.x + av.y * w1v.y + av.z * w1v.z + av.w * w1v.w;
            uint2 pv;
            pv.x = cvt_pk_bf16(av.x * w3v.x, av.y * w3v.y);
            pv.y = cvt_pk_bf16(av.z * w3v.z, av.w * w3v.w);
            *(uint2*)(&As[row * LDK + d0]) = pv;
            if (pref) Apre[i] = *(const float4*)(ctx_base + (size_t)row * H2c + kdc);

            float4 bv = Bpre[i];
            saspp[i] += bv.x * w2v.x + bv.y * w2v.y + bv.z * w2v.z + bv.w * w2v.w;
            uint2 qv;
            qv.x = cvt_pk_bf16(bv.x, bv.y);
            qv.y = cvt_pk_bf16(bv.z, bv.w);
            *(uint2*)(&Bs[row * LDK + d0]) = qv;
            if (pref) Bpre[i] = *(const float4*)(asp_base + (size_t)row * H2c + kdc);
        }
        if (pref) {
            const float4 z4 = make_float4(0.f, 0.f, 0.f, 0.f);
            w1v = wval ? *(const float4*)(w1 + kdc) : z4;
            w2v = wval ? *(const float4*)(w2 + kdc) : z4;
            w3v = wval ? *(const float4*)(w3 + kdc) : z4;
        }
        __syncthreads();   // staged tile visible to all waves

        // ---- MFMA: 2 k-steps of 32; wave computes 32x64 as 2x4 of 16x16 ----
#pragma unroll
        for (int ks = 0; ks < 2; ks++) {
            const int kk = ks * 32 + quad * 8;   // A/B frag: [m=lane&15][k=quad*8+j]
            bf16x8 afr[2], bfr[4];
#pragma unroll
            for (int t = 0; t < 2; t++)
                afr[t] = *(const bf16x8*)(&As[(wm * 32 + t * 16 + l15) * LDK + kk]);
#pragma unroll
            for (int t = 0; t < 4; t++)
                bfr[t] = *(const bf16x8*)(&Bs[(wn * 64 + t * 16 + l15) * LDK + kk]);
#pragma unroll
            for (int tm = 0; tm < 2; tm++)
#pragma unroll
                for (int tn = 0; tn < 4; tn++)
                    acc[tm][tn] = __builtin_amdgcn_mfma_f32_16x16x32_bf16(
                        afr[tm], bfr[tn], acc[tm][tn], 0, 0, 0);
        }
        __syncthreads();
    }

    // ---- reduce s_ctx / s_asp partials (reuse As as scratch: 128x16 f32 = 8 KB) ----
    float* red = (float*)As;
#pragma unroll
    for (int i = 0; i < 4; i++) red[(srow + i * 32) * 16 + scg] = sctxp[i];
    __syncthreads();
    if (tid < BM) {
        float s = 0.f;
#pragma unroll
        for (int c = 0; c < 16; c++) s += red[tid * 16 + c];
        sA[tid] = s;
    }
    __syncthreads();
#pragma unroll
    for (int i = 0; i < 4; i++) red[(srow + i * 32) * 16 + scg] = saspp[i];
    __syncthreads();
    if (tid < BN) {
        float s = 0.f;
#pragma unroll
        for (int c = 0; c < 16; c++) s += red[tid * 16 + c];
        sB[tid] = s;
    }
    __syncthreads();

    // ---- epilogue: D mapping col=lane&15, row=quad*4+reg; add s_ctx[m] + s_asp[n] ----
    float* out_base = out + ((size_t)b * L1c + rowBase) * L2c;
#pragma unroll
    for (int tm = 0; tm < 2; tm++) {
#pragma unroll
        for (int tn = 0; tn < 4; tn++) {
            const int col = wn * 64 + tn * 16 + l15;
            const float sbv = sB[col];
#pragma unroll
            for (int r = 0; r < 4; r++) {
                const int m = wm * 32 + tm * 16 + quad * 4 + r;
                out_base[(size_t)m * L2c + col] = acc[tm][tn][r] + sA[m] + sbv;
            }
        }
    }
}

extern "C" void kernel_launch(void* const* d_in, const int* in_sizes, int n_in,
                              void* d_out, int out_size, void* d_ws, size_t ws_size,
                              hipStream_t stream) {
    // inputs: [0]=batch_size (int scalar), [1]=ctx f32, [2]=asp f32, [3]=w_u f32
    const float* ctx = (const float*)d_in[1];
    const float* asp = (const float*)d_in[2];
    const float* w_u = (const float*)d_in[3];
    float* out = (float*)d_out;

    dim3 grid(L1c / BM * Bn);   // 1024 blocks (flat, XCD-swizzled in-kernel), 512 threads
    align_kernel<<<grid, 512, 0, stream>>>(ctx, asp, w_u, out);
}

// Round 2
// 496.800 us; speedup vs baseline: 1.5941x; 1.5941x over previous
//
#include <hip/hip_runtime.h>
#include <hip/hip_bf16.h>

// Problem constants (AlignmentMatrix): B=128, L1=1024, L2=128, H2=600
static constexpr int Bn  = 128;
static constexpr int L1c = 1024;
static constexpr int L2c = 128;
static constexpr int H2c = 600;

#define BM 128
#define BN 128
#define BK 64
#define LDK 72              // BK + 8 pad shorts; row stride 144 B (16B-aligned, non-pow2 banks)
static constexpr int NCHUNK = (H2c + BK - 1) / BK;   // 10 (last chunk: 24 valid cols, zero-padded)

typedef __attribute__((ext_vector_type(8))) __bf16 bf16x8;
typedef __attribute__((ext_vector_type(4))) float  f32x4;

__device__ __forceinline__ unsigned short f2bf(float f) {
    // round-to-nearest-even f32 -> bf16
    unsigned int u = __float_as_uint(f);
    u += 0x7FFFu + ((u >> 16) & 1u);
    return (unsigned short)(u >> 16);
}

// 512 threads = 8 waves in a 4x2 grid of 32x64 sub-tiles.
// Pipeline: regs hold chunk k at loop top -> convert+ds_write -> barrier ->
// issue chunk k+1 loads (in flight during MFMA) -> MFMA -> barrier.
// ROUND-0 proven structure; ONLY delta this round = XCD-bijective block decode.
__global__ __launch_bounds__(512, 4)
void align_kernel(const float* __restrict__ ctx, const float* __restrict__ asp,
                  const float* __restrict__ w_u, float* __restrict__ out)
{
    __shared__ unsigned short As[BM * LDK];   // 18432 B, (ctx*w3) in bf16
    __shared__ unsigned short Bs[BN * LDK];   // 18432 B, asp in bf16
    __shared__ float sA[BM];                  // s_ctx for block rows
    __shared__ float sB[BN];                  // s_asp for block cols

    // XCD-aware bijective decode (ONLY change vs round-0):
    // id = 8*(rt + 8*bq) + xcd ; b = xcd + 8*bq ; rowBase = rt*BM.
    // HW round-robins flattened id -> XCD (id & 7). All 8 row-tiles sharing
    // asp[b] (300 KB) now land on XCD (b & 7); per-XCD asp working set
    // ~16 batches x 300 KB with 8x line reuse -> asp fetched ~once from HBM.
    const int id   = blockIdx.x;
    const int xcd  = id & 7;
    const int slot = id >> 3;
    const int rt   = slot & 7;    // row tile 0..7
    const int bq   = slot >> 3;   // 0..15
    const int b    = xcd + 8 * bq;
    const int rowBase = rt * BM;

    const int tid  = threadIdx.x;
    const int lane = tid & 63;
    const int wave = tid >> 6;     // 0..7
    const int wm   = wave >> 1;    // 0..3: 32-row band
    const int wn   = wave & 1;     // 0..1: 64-col half
    const int quad = lane >> 4;
    const int l15  = lane & 15;

    const float* ctx_base = ctx + ((size_t)b * L1c + rowBase) * H2c;
    const float* asp_base = asp + (size_t)b * L2c * H2c;
    const float* w1 = w_u;
    const float* w2 = w_u + H2c;
    const float* w3 = w_u + 2 * H2c;

    // staging: thread (srow,scg) covers rows {srow+32i, i<4}, cols [scg*4, scg*4+3]
    const int srow = tid >> 4;     // 0..31
    const int scg  = tid & 15;     // 0..15
    const int d0   = scg * 4;      // 0..60

    f32x4 acc[2][4];
    const f32x4 zero4 = {0.f, 0.f, 0.f, 0.f};
#pragma unroll
    for (int i = 0; i < 2; i++)
#pragma unroll
        for (int j = 0; j < 4; j++) acc[i][j] = zero4;

    float sctxp[4], saspp[4];
#pragma unroll
    for (int i = 0; i < 4; i++) { sctxp[i] = 0.f; saspp[i] = 0.f; }

    float4 Apre[4], Bpre[4], w1v, w2v, w3v;

    // ---- prologue: load chunk 0 (always fully valid) ----
    {
        const int kd = d0;
        w1v = *(const float4*)(w1 + kd);
        w2v = *(const float4*)(w2 + kd);
        w3v = *(const float4*)(w3 + kd);
#pragma unroll
        for (int i = 0; i < 4; i++) {
            const int row = srow + i * 32;
            Apre[i] = *(const float4*)(ctx_base + row * H2c + kd);
            Bpre[i] = *(const float4*)(asp_base + row * H2c + kd);
        }
    }

    for (int kc = 0; kc < NCHUNK; kc++) {
        // ---- convert + write chunk kc from regs; fuse rank-1 partial dots ----
#pragma unroll
        for (int i = 0; i < 4; i++) {
            const int row = srow + i * 32;
            float4 av = Apre[i];
            sctxp[i] += av.x * w1v.x + av.y * w1v.y + av.z * w1v.z + av.w * w1v.w;
            ushort4 pv;
            pv.x = f2bf(av.x * w3v.x);
            pv.y = f2bf(av.y * w3v.y);
            pv.z = f2bf(av.z * w3v.z);
            pv.w = f2bf(av.w * w3v.w);
            *(ushort4*)(&As[row * LDK + d0]) = pv;

            float4 bv = Bpre[i];
            saspp[i] += bv.x * w2v.x + bv.y * w2v.y + bv.z * w2v.z + bv.w * w2v.w;
            ushort4 qv;
            qv.x = f2bf(bv.x);
            qv.y = f2bf(bv.y);
            qv.z = f2bf(bv.z);
            qv.w = f2bf(bv.w);
            *(ushort4*)(&Bs[row * LDK + d0]) = qv;
        }
        __syncthreads();   // staged tile visible to all waves

        // ---- issue chunk kc+1 loads NOW: in flight during the MFMA phase ----
        if (kc + 1 < NCHUNK) {
            const int kd = (kc + 1) * BK + d0;
            const bool valid = (kd < H2c);   // whole float4 valid or not (H2c%4==0)
            const float4 z4 = make_float4(0.f, 0.f, 0.f, 0.f);
            w1v = valid ? *(const float4*)(w1 + kd) : z4;
            w2v = valid ? *(const float4*)(w2 + kd) : z4;
            w3v = valid ? *(const float4*)(w3 + kd) : z4;
#pragma unroll
            for (int i = 0; i < 4; i++) {
                const int row = srow + i * 32;
                Apre[i] = valid ? *(const float4*)(ctx_base + row * H2c + kd) : z4;
                Bpre[i] = valid ? *(const float4*)(asp_base + row * H2c + kd) : z4;
            }
        }

        // ---- MFMA: 2 k-steps of 32; wave computes 32x64 as 2x4 of 16x16 ----
#pragma unroll
        for (int ks = 0; ks < 2; ks++) {
            const int kk = ks * 32 + quad * 8;   // A/B frag: [m=lane&15][k=quad*8+j]
            bf16x8 afr[2], bfr[4];
#pragma unroll
            for (int t = 0; t < 2; t++)
                afr[t] = *(const bf16x8*)(&As[(wm * 32 + t * 16 + l15) * LDK + kk]);
#pragma unroll
            for (int t = 0; t < 4; t++)
                bfr[t] = *(const bf16x8*)(&Bs[(wn * 64 + t * 16 + l15) * LDK + kk]);
#pragma unroll
            for (int tm = 0; tm < 2; tm++)
#pragma unroll
                for (int tn = 0; tn < 4; tn++)
                    acc[tm][tn] = __builtin_amdgcn_mfma_f32_16x16x32_bf16(
                        afr[tm], bfr[tn], acc[tm][tn], 0, 0, 0);
        }
        __syncthreads();
    }

    // ---- reduce s_ctx / s_asp partials (reuse As as scratch: 128x16 f32 = 8 KB) ----
    float* red = (float*)As;
#pragma unroll
    for (int i = 0; i < 4; i++) red[(srow + i * 32) * 16 + scg] = sctxp[i];
    __syncthreads();
    if (tid < BM) {
        float s = 0.f;
#pragma unroll
        for (int c = 0; c < 16; c++) s += red[tid * 16 + c];
        sA[tid] = s;
    }
    __syncthreads();
#pragma unroll
    for (int i = 0; i < 4; i++) red[(srow + i * 32) * 16 + scg] = saspp[i];
    __syncthreads();
    if (tid < BN) {
        float s = 0.f;
#pragma unroll
        for (int c = 0; c < 16; c++) s += red[tid * 16 + c];
        sB[tid] = s;
    }
    __syncthreads();

    // ---- epilogue: D mapping col=lane&15, row=quad*4+reg; add s_ctx[m] + s_asp[n] ----
    float* out_base = out + ((size_t)b * L1c + rowBase) * L2c;
#pragma unroll
    for (int tm = 0; tm < 2; tm++) {
#pragma unroll
        for (int tn = 0; tn < 4; tn++) {
            const int col = wn * 64 + tn * 16 + l15;
            const float sbv = sB[col];
#pragma unroll
            for (int r = 0; r < 4; r++) {
                const int m = wm * 32 + tm * 16 + quad * 4 + r;
                out_base[(size_t)m * L2c + col] = acc[tm][tn][r] + sA[m] + sbv;
            }
        }
    }
}

extern "C" void kernel_launch(void* const* d_in, const int* in_sizes, int n_in,
                              void* d_out, int out_size, void* d_ws, size_t ws_size,
                              hipStream_t stream) {
    // inputs: [0]=batch_size (int scalar), [1]=ctx f32, [2]=asp f32, [3]=w_u f32
    const float* ctx = (const float*)d_in[1];
    const float* asp = (const float*)d_in[2];
    const float* w_u = (const float*)d_in[3];
    float* out = (float*)d_out;

    dim3 grid(L1c / BM * Bn);   // 1024 blocks flat; XCD-bijective decode in-kernel
    align_kernel<<<grid, 512, 0, stream>>>(ctx, asp, w_u, out);
}